// Round 3
// baseline (1134.234 us; speedup 1.0000x reference)
//
#include <hip/hip_runtime.h>
#include <math.h>

typedef _Float16 f16;
typedef _Float16 f16x4 __attribute__((ext_vector_type(4)));
typedef _Float16 f16x8 __attribute__((ext_vector_type(8)));
typedef float    f32x4 __attribute__((ext_vector_type(4)));

#define N_ROWS 16000
#define DIM    256
#define BATCH  4096
#define TK     64
#define NTILE  250      // 16000/64
#define PSTR   72       // shP row stride (f16): 4(l15+quad) bank starts, conflict-min

// async 16B global->LDS copy (LDS dest = uniform base + lane*16)
#define ASYNC_CP16(gsrc, ldst) \
  __builtin_amdgcn_global_load_lds((const __attribute__((address_space(1))) unsigned int*)(gsrc), \
                                   (__attribute__((address_space(3))) unsigned int*)(ldst), 16, 0, 0)

// ---------------- pack: fp32 -> f16, XOR-swizzled row-major K + tile-transposed V ----
// K layout: [mat][row][chunk' = chunk ^ (row&7)][8 f16]   (chunk = 16B unit, 32/row)
// V layout: [mat][tile][d][chunk' = chunk ^ (d&7)][8 f16]  (chunk = 16B unit, 8/row of 64 kv)
__global__ __launch_bounds__(256) void k_pack(
    const float* __restrict__ m0, const float* __restrict__ m1, const float* __restrict__ m2,
    const float* __restrict__ m3, const float* __restrict__ m4, const float* __restrict__ m5,
    f16* __restrict__ Kbf, f16* __restrict__ Vt)
{
  __shared__ f16 lt[64][72];   // [n-local][d-local]
  const float* mats[6] = {m0, m1, m2, m3, m4, m5};
  int bid = blockIdx.x;                 // 6 * 250 * 4
  int db  = bid & 3;                    // d block (64 cols)
  int tn  = (bid >> 2) % NTILE;         // n tile (64 rows)
  int me  = bid / (NTILE * 4);
  const float* src = mats[me];
  int tid = threadIdx.x;
#pragma unroll
  for (int i = 0; i < 4; ++i) {
    int cidx = i * 256 + tid;           // 1024 chunks of 4 floats: 64 rows x 16 chunks
    int r = cidx >> 4, cc = (cidx & 15) * 4;
    float4 f = *(const float4*)(src + (size_t)(tn * 64 + r) * DIM + db * 64 + cc);
    f16x4 h = {(f16)f.x, (f16)f.y, (f16)f.z, (f16)f.w};
    *(f16x4*)&lt[r][cc] = h;
    int colK = db * 64 + (((cc >> 3) ^ (r & 7)) << 3) + (cc & 7);   // swizzled col
    *(f16x4*)(Kbf + (size_t)me * N_ROWS * DIM + (size_t)(tn * 64 + r) * DIM + colK) = h;
  }
  __syncthreads();
#pragma unroll
  for (int i = 0; i < 4; ++i) {
    int cidx = i * 256 + tid;           // 64 d x 16 n-chunks
    int dl = cidx >> 4, nc4 = (cidx & 15) * 4;
    f16x4 hv = { lt[nc4 + 0][dl], lt[nc4 + 1][dl], lt[nc4 + 2][dl], lt[nc4 + 3][dl] };
    int colV = (((nc4 >> 3) ^ (dl & 7)) << 3) + (nc4 & 7);          // swizzled kv col
    *(f16x4*)(Vt + ((size_t)(me * NTILE + tn) * DIM + db * 64 + dl) * TK + colV) = hv;
  }
}

// ---------------- gather Q rows to f16 ----------------
__global__ __launch_bounds__(256) void k_gather(
    const float* __restrict__ m0, const float* __restrict__ m1, const float* __restrict__ m2,
    const float* __restrict__ m3, const float* __restrict__ m4, const float* __restrict__ m5,
    const int* __restrict__ batch, f16* __restrict__ Qg)
{
  const float* mats[6] = {m0, m1, m2, m3, m4, m5};
  int gid  = blockIdx.x * 4 + (threadIdx.x >> 6);   // row id 0..24575 (cs*4096+b)
  int lane = threadIdx.x & 63;
  int s   = gid / (3 * BATCH);
  int rem = gid - s * 3 * BATCH;
  int c   = rem / BATCH;
  int b   = rem - c * BATCH;
  int idx = batch[(size_t)b * 2 + s];
  const float* src = mats[(s == 0 ? 0 : 3) + c] + (size_t)idx * DIM;
  float4 f = *(const float4*)(src + lane * 4);
  f16x4 h = {(f16)f.x, (f16)f.y, (f16)f.z, (f16)f.w};
  *(f16x4*)(Qg + (size_t)gid * DIM + lane * 4) = h;
}

// ---------------- flash attention: 32 q-rows/wave, 4 KV slices, atomic combine ------
__global__ __launch_bounds__(256, 2) void k_attn(
    const f16* __restrict__ Kbf, const f16* __restrict__ Vt,
    const f16* __restrict__ Qg, float* __restrict__ Re, float* __restrict__ lacc)
{
  __shared__ __align__(16) char smem[65536];
  char* shK = smem;              // 64 kv x 512B (swizzled chunks)
  char* shV = smem + 32768;      // 256 d x 128B (swizzled chunks)
  f16*  shP = (f16*)smem;        // overlay on shK: [4 waves][32 q][PSTR]

  const int bid = blockIdx.x;    // 768 = 6(cs) * 32(qtile of 128) * 4(slice)
  const int v  = bid & 3;
  const int t  = (bid >> 2) & 31;
  const int cs = bid >> 7;       // s*3+c
  const int s  = cs / 3, c = cs - s * 3;
  const int kvmat = (s == 0) ? (3 + c) : c;

  const int tid  = threadIdx.x;
  const int lane = tid & 63;
  const int w    = tid >> 6;
  const int l15  = lane & 15;
  const int quad = lane >> 4;
  const int e3   = l15 & 7;      // swizzle key

  // Q fragments: 2 m-tiles x 8 k-chunks (A-layout: A[m=l15][k=quad*8+j])
  const f16* Qbase = Qg + ((size_t)cs * BATCH + (size_t)t * 128 + w * 32) * DIM;
  f16x8 qf[2][8];
#pragma unroll
  for (int mt = 0; mt < 2; ++mt)
#pragma unroll
    for (int kt = 0; kt < 8; ++kt)
      qf[mt][kt] = *(const f16x8*)(Qbase + (mt * 16 + l15) * DIM + kt * 32 + quad * 8);

  f32x4 O[2][16];
#pragma unroll
  for (int mt = 0; mt < 2; ++mt)
#pragma unroll
    for (int i = 0; i < 16; ++i) O[mt][i] = (f32x4){0.f, 0.f, 0.f, 0.f};
  float m_[2][4] = {{-INFINITY,-INFINITY,-INFINITY,-INFINITY},
                    {-INFINITY,-INFINITY,-INFINITY,-INFINITY}};
  float l_[2][4] = {{0.f,0.f,0.f,0.f},{0.f,0.f,0.f,0.f}};

  const char* gK0 = (const char*)Kbf + (size_t)kvmat * N_ROWS * DIM * 2;
  const char* gV0 = (const char*)Vt  + (size_t)kvmat * NTILE * DIM * TK * 2;

  // slice tile range: 63,63,62,62
  const int t0 = v * 62 + (v < 2 ? v : 2);
  const int t1 = (v + 1) * 62 + (v < 1 ? v + 1 : 2);

  for (int tile = t0; tile < t1; ++tile) {
    // ---- stage K,V tiles: verbatim 32KB copies via global_load_lds ----
    {
      const char* gK = gK0 + (size_t)tile * 32768;
      const char* gV = gV0 + (size_t)tile * 32768;
#pragma unroll
      for (int i = 0; i < 8; ++i) {
        int off = w * 8192 + i * 1024;
        ASYNC_CP16(gK + off + lane * 16, shK + off);
      }
#pragma unroll
      for (int i = 0; i < 8; ++i) {
        int off = w * 8192 + i * 1024;
        ASYNC_CP16(gV + off + lane * 16, shV + off);
      }
    }
    __syncthreads();   // bar1: DMA drained (vmcnt(0) before s_barrier)

    // ---- S = Q K^T : 32 x 64 per wave; kf reused across both m-tiles ----
    f32x4 sacc[2][4];
#pragma unroll
    for (int mt = 0; mt < 2; ++mt)
#pragma unroll
      for (int nc = 0; nc < 4; ++nc) sacc[mt][nc] = (f32x4){0.f, 0.f, 0.f, 0.f};
#pragma unroll
    for (int kt = 0; kt < 8; ++kt) {
#pragma unroll
      for (int nc = 0; nc < 4; ++nc) {
        f16x8 kf = *(const f16x8*)(shK + ((16 * nc + l15) << 9) + ((((kt << 2) + quad) ^ e3) << 4));
        sacc[0][nc] = __builtin_amdgcn_mfma_f32_16x16x32_f16(qf[0][kt], kf, sacc[0][nc], 0, 0, 0);
        sacc[1][nc] = __builtin_amdgcn_mfma_f32_16x16x32_f16(qf[1][kt], kf, sacc[1][nc], 0, 0, 0);
      }
    }
    __syncthreads();   // bar2: all QK reads of shK done -> safe to overwrite with P

    // ---- online softmax per m-tile; P -> LDS (C-layout -> row-major) ----
    bool upd = false;
    float alpha[2][4];
#pragma unroll
    for (int mt = 0; mt < 2; ++mt) {
#pragma unroll
      for (int r = 0; r < 4; ++r) {
        float mx = fmaxf(fmaxf(sacc[mt][0][r], sacc[mt][1][r]),
                         fmaxf(sacc[mt][2][r], sacc[mt][3][r]));
#pragma unroll
        for (int off = 1; off < 16; off <<= 1) mx = fmaxf(mx, __shfl_xor(mx, off, 64));
        float mnew = fmaxf(m_[mt][r], mx);
        alpha[mt][r] = __expf(m_[mt][r] - mnew);
        upd = upd || (mnew > m_[mt][r]);
        m_[mt][r] = mnew;
      }
      float rowsum[4] = {0.f, 0.f, 0.f, 0.f};
#pragma unroll
      for (int nc = 0; nc < 4; ++nc) {
#pragma unroll
        for (int r = 0; r < 4; ++r) {
          float p = __expf(sacc[mt][nc][r] - m_[mt][r]);
          rowsum[r] += p;
          shP[w * 2304 + (quad * 4 + r + 16 * mt) * PSTR + nc * 16 + l15] = (f16)p;
        }
      }
#pragma unroll
      for (int r = 0; r < 4; ++r) {
#pragma unroll
        for (int off = 1; off < 16; off <<= 1) rowsum[r] += __shfl_xor(rowsum[r], off, 64);
        l_[mt][r] = l_[mt][r] * alpha[mt][r] + rowsum[r];
      }
    }
    if (__any(upd)) {
#pragma unroll
      for (int mt = 0; mt < 2; ++mt)
#pragma unroll
        for (int nc = 0; nc < 16; ++nc)
#pragma unroll
          for (int r = 0; r < 4; ++r) O[mt][nc][r] *= alpha[mt][r];
    }

    // ---- O += P V  (vf reused across both m-tiles) ----
    f16x8 pf[2][2];
#pragma unroll
    for (int mt = 0; mt < 2; ++mt)
#pragma unroll
      for (int h = 0; h < 2; ++h)
        pf[mt][h] = *(const f16x8*)(shP + w * 2304 + (l15 + 16 * mt) * PSTR + quad * 8 + 32 * h);
#pragma unroll
    for (int h = 0; h < 2; ++h) {
#pragma unroll
      for (int nc = 0; nc < 16; ++nc) {
        f16x8 vf = *(const f16x8*)(shV + ((16 * nc + l15) << 7) + (((quad + 4 * h) ^ e3) << 4));
        O[0][nc] = __builtin_amdgcn_mfma_f32_16x16x32_f16(pf[0][h], vf, O[0][nc], 0, 0, 0);
        O[1][nc] = __builtin_amdgcn_mfma_f32_16x16x32_f16(pf[1][h], vf, O[1][nc], 0, 0, 0);
      }
    }
    __syncthreads();   // bar3: PV reads (shV) + P region done before next stage
  }

  // ---- epilogue: fixed-offset (e^{m-80}) atomic accumulation ----
  const int rowbase = cs * BATCH + t * 128 + w * 32;
#pragma unroll
  for (int mt = 0; mt < 2; ++mt) {
#pragma unroll
    for (int r = 0; r < 4; ++r) {
      int grow = rowbase + mt * 16 + quad * 4 + r;
      float scale = __expf(m_[mt][r] - 80.0f);
      if (l15 == 0) atomicAdd(&lacc[grow], l_[mt][r] * scale);
#pragma unroll
      for (int nc = 0; nc < 16; ++nc)
        atomicAdd(&Re[(size_t)grow * DIM + nc * 16 + l15], O[mt][nc][r] * scale);
    }
  }
}

// ---------------- combine: Re/l + residual + MLP -> sigmoid scalar ----------------
__global__ __launch_bounds__(256, 2) void k_combine(
    const float* __restrict__ W1, const float* __restrict__ b1,
    const float* __restrict__ W2, const float* __restrict__ b2,
    const f16* __restrict__ Qg, const float* __restrict__ Re,
    const float* __restrict__ lacc, float* __restrict__ mval)
{
  __shared__ f16 w1s[DIM * 128];
  __shared__ float reb[4][DIM];
  __shared__ float w2s[128];
  __shared__ float b1s[128];
  int tid = threadIdx.x;
#pragma unroll
  for (int i = 0; i < 32; ++i) {
    int e = i * 1024 + tid * 4;
    float4 f = *(const float4*)(W1 + e);
    f16x4 h = {(f16)f.x, (f16)f.y, (f16)f.z, (f16)f.w};
    *(f16x4*)&w1s[e] = h;
  }
  if (tid < 128) { w2s[tid] = W2[tid]; b1s[tid] = b1[tid]; }
  float b2v = b2[0];
  __syncthreads();

  int w = tid >> 6, lane = tid & 63;
  for (int rr = 0; rr < 8; ++rr) {
    int grow = blockIdx.x * 32 + w * 8 + rr;       // cs*4096+q, 0..24575
    float inv = 1.f / lacc[grow];
    float4 o4 = *(const float4*)(Re + (size_t)grow * DIM + lane * 4);
    f16x4 qv = *(const f16x4*)(Qg + (size_t)grow * DIM + lane * 4);
    reb[w][lane * 4 + 0] = o4.x * inv + (float)qv[0];
    reb[w][lane * 4 + 1] = o4.y * inv + (float)qv[1];
    reb[w][lane * 4 + 2] = o4.z * inv + (float)qv[2];
    reb[w][lane * 4 + 3] = o4.w * inv + (float)qv[3];
    // wave-local LDS: same-wave ds ops are in-order, no barrier needed
    float acc0 = b1s[lane], acc1 = b1s[lane + 64];
    for (int d = 0; d < DIM; ++d) {
      float rv = reb[w][d];
      acc0 += rv * (float)w1s[d * 128 + lane];
      acc1 += rv * (float)w1s[d * 128 + 64 + lane];
    }
    float part = fmaxf(acc0, 0.f) * w2s[lane] + fmaxf(acc1, 0.f) * w2s[lane + 64];
#pragma unroll
    for (int off = 1; off < 64; off <<= 1) part += __shfl_xor(part, off, 64);
    if (lane == 0) mval[grow] = 1.f / (1.f + __expf(-(part + b2v)));
  }
}

// ---------------- copy all 6 arrays to out ----------------
__global__ __launch_bounds__(256) void k_copy(
    const float* __restrict__ m0, const float* __restrict__ m1, const float* __restrict__ m2,
    const float* __restrict__ m3, const float* __restrict__ m4, const float* __restrict__ m5,
    float* __restrict__ out)
{
  const float* mats[6] = {m0, m1, m2, m3, m4, m5};
  int arr = blockIdx.x / 4000;
  int chunk = (blockIdx.x - arr * 4000) * 256 + threadIdx.x;
  float4 v = *(const float4*)(mats[arr] + (size_t)chunk * 4);
  *(float4*)(out + (size_t)arr * 4096000 + (size_t)chunk * 4) = v;
}

// ---------------- kg softmax + scaled row scatter ----------------
__global__ __launch_bounds__(256) void k_scatter(
    const float* __restrict__ m0, const float* __restrict__ m1, const float* __restrict__ m2,
    const float* __restrict__ m3, const float* __restrict__ m4, const float* __restrict__ m5,
    const int* __restrict__ batch, const float* __restrict__ mval,
    float* __restrict__ out)
{
  const float* mats[6] = {m0, m1, m2, m3, m4, m5};
  int gid  = blockIdx.x * 4 + (threadIdx.x >> 6);   // 0..8191 = s*4096+b
  int lane = threadIdx.x & 63;
  int s = gid >> 12;
  int b = gid & 4095;
  int idx = batch[(size_t)b * 2 + s];
  float v0 = mval[(s * 3 + 0) * BATCH + b];
  float v1 = mval[(s * 3 + 1) * BATCH + b];
  float v2 = mval[(s * 3 + 2) * BATCH + b];
  float mx = fmaxf(v0, fmaxf(v1, v2));
  float e0 = __expf(v0 - mx), e1 = __expf(v1 - mx), e2 = __expf(v2 - mx);
  float inv = 1.f / (e0 + e1 + e2);
  float kgn = e1 * inv;
  float kgo = e2 * inv;
  int a1 = s * 3 + 1, a2 = s * 3 + 2;
  const float* s1 = mats[a1] + (size_t)idx * DIM;
  const float* s2 = mats[a2] + (size_t)idx * DIM;
  float4 f1 = *(const float4*)(s1 + lane * 4);
  float4 f2 = *(const float4*)(s2 + lane * 4);
  float4 r1 = {f1.x * kgn, f1.y * kgn, f1.z * kgn, f1.w * kgn};
  float4 r2 = {f2.x * kgo, f2.y * kgo, f2.z * kgo, f2.w * kgo};
  *(float4*)(out + (size_t)a1 * 4096000 + (size_t)idx * DIM + lane * 4) = r1;
  *(float4*)(out + (size_t)a2 * 4096000 + (size_t)idx * DIM + lane * 4) = r2;
}

extern "C" void kernel_launch(void* const* d_in, const int* in_sizes, int n_in,
                              void* d_out, int out_size, void* d_ws, size_t ws_size,
                              hipStream_t stream)
{
  const float* x1  = (const float*)d_in[0];
  const float* xn1 = (const float*)d_in[1];
  const float* oh1 = (const float*)d_in[2];
  const float* x2  = (const float*)d_in[3];
  const float* xn2 = (const float*)d_in[4];
  const float* oh2 = (const float*)d_in[5];
  const float* W1  = (const float*)d_in[6];
  const float* b1  = (const float*)d_in[7];
  const float* W2  = (const float*)d_in[8];
  const float* b2  = (const float*)d_in[9];
  const int*   batch = (const int*)d_in[10];
  float* out = (float*)d_out;

  // Packed K/V scratch fills d_out exactly (98,304,000 B); fully consumed before k_copy.
  f16* Kbf = (f16*)d_out;
  f16* Vt  = (f16*)((char*)d_out + 49152000);

  // d_ws layout: 37,945,344 B total (proven ws_size >= 38,240,256)
  char* ws = (char*)d_ws;
  float* Re   = (float*)(ws);               // 24576*256 f32 = 25,165,824 B
  float* lacc = (float*)(ws + 25165824);    // 24576 f32     =     98,304 B
  f16*   Qg   = (f16*)(ws + 25264128);      // 24576*256 f16 = 12,582,912 B
  float* mval = (float*)(ws + 37847040);    // 24576 f32     =     98,304 B

  hipMemsetAsync(Re, 0, 25264128, stream);  // zero Re + lacc (adjacent)

  k_pack   <<<6000, 256, 0, stream>>>(x1, xn1, oh1, x2, xn2, oh2, Kbf, Vt);
  k_gather <<<6144, 256, 0, stream>>>(x1, xn1, oh1, x2, xn2, oh2, batch, Qg);
  k_attn   <<<768,  256, 0, stream>>>(Kbf, Vt, Qg, Re, lacc);
  k_combine<<<768,  256, 0, stream>>>(W1, b1, W2, b2, Qg, Re, lacc, mval);
  k_copy   <<<24000, 256, 0, stream>>>(x1, xn1, oh1, x2, xn2, oh2, out);
  k_scatter<<<2048, 256, 0, stream>>>(x1, xn1, oh1, x2, xn2, oh2, batch, mval, out);
}